// Round 1
// baseline (255.321 us; speedup 1.0000x reference)
//
#include <hip/hip_runtime.h>

// out = x @ H, H = 4096x4096 Sylvester Hadamard (+/-1). Since
// H[i][j] = (-1)^popcount(i&j) is symmetric, each output row is the
// Walsh-Hadamard transform of the input row -> O(N log N) butterflies
// instead of a 275-GFLOP fp32 matmul. Memory-bound: 256 MiB total traffic,
// roofline ~43 us at 6.3 TB/s. H (d_in[1]) is never read.

constexpr int N = 4096;

// LDS bank-conflict swizzle: XOR bits 6-8 of the element index into bits 2-4.
// Phase-0 float4 writes: every aligned 8-lane group covers all 8 bank-quads
// (conflict-free); phase-1/2 scalar reads/writes: exactly 2 lanes/bank per
// wave (2-way aliasing is free on gfx950, m136).
__device__ __forceinline__ int swz(int i) {
    return i ^ (((i >> 6) & 7) << 2);
}

__global__ __launch_bounds__(256) void fwht4096_kernel(const float* __restrict__ x,
                                                       float* __restrict__ out) {
    __shared__ __align__(16) float lds[N];
    const int t = threadIdx.x;
    const size_t rowoff = (size_t)blockIdx.x * N;
    const float* __restrict__ xr = x + rowoff;
    float* __restrict__ yr = out + rowoff;

    // ---- Phase 0: load i = 1024k + 4t + j (coalesced float4), do stages on
    // bits 0,1 (j) and 10,11 (k): h = 1, 2, 1024, 2048.
    float r[4][4];
#pragma unroll
    for (int k = 0; k < 4; ++k) {
        const float4 v = *reinterpret_cast<const float4*>(xr + 1024 * k + 4 * t);
        r[k][0] = v.x; r[k][1] = v.y; r[k][2] = v.z; r[k][3] = v.w;
    }
#pragma unroll
    for (int k = 0; k < 4; ++k) {  // h=1 then h=2 (bits 0-1)
        float a0 = r[k][0] + r[k][1];
        float a1 = r[k][0] - r[k][1];
        float a2 = r[k][2] + r[k][3];
        float a3 = r[k][2] - r[k][3];
        r[k][0] = a0 + a2;
        r[k][1] = a1 + a3;
        r[k][2] = a0 - a2;
        r[k][3] = a1 - a3;
    }
#pragma unroll
    for (int j = 0; j < 4; ++j) {  // h=1024 then h=2048 (bits 10-11)
        float a0 = r[0][j] + r[1][j];
        float a1 = r[0][j] - r[1][j];
        float a2 = r[2][j] + r[3][j];
        float a3 = r[2][j] - r[3][j];
        r[0][j] = a0 + a2;
        r[1][j] = a1 + a3;
        r[2][j] = a0 - a2;
        r[3][j] = a1 - a3;
    }
#pragma unroll
    for (int k = 0; k < 4; ++k) {
        const int i0 = 1024 * k + 4 * t;  // swz preserves low 2 bits & 16B align
        *reinterpret_cast<float4*>(&lds[swz(i0)]) =
            make_float4(r[k][0], r[k][1], r[k][2], r[k][3]);
    }
    __syncthreads();

    // ---- Phase 1: own bits 2-5 (m), stages h = 4, 8, 16, 32.
    float v[16];
    const int base1 = (t & 3) | (((t >> 2) & 15) << 6) | ((t >> 6) << 10);
#pragma unroll
    for (int m = 0; m < 16; ++m) v[m] = lds[swz(base1 | (m << 2))];
#pragma unroll
    for (int b = 1; b < 16; b <<= 1) {
#pragma unroll
        for (int m = 0; m < 16; ++m) {
            if ((m & b) == 0) {
                const float a = v[m], c = v[m | b];
                v[m]     = a + c;
                v[m | b] = a - c;
            }
        }
    }
#pragma unroll
    for (int m = 0; m < 16; ++m) lds[swz(base1 | (m << 2))] = v[m];
    __syncthreads();

    // ---- Phase 2: own bits 6-9 (m), stages h = 64, 128, 256, 512.
    float w[16];
    const int base2 = (t & 63) | ((t >> 6) << 10);
#pragma unroll
    for (int m = 0; m < 16; ++m) w[m] = lds[swz(base2 | (m << 6))];
#pragma unroll
    for (int b = 1; b < 16; b <<= 1) {
#pragma unroll
        for (int m = 0; m < 16; ++m) {
            if ((m & b) == 0) {
                const float a = w[m], c = w[m | b];
                w[m]     = a + c;
                w[m | b] = a - c;
            }
        }
    }
    // Coalesced dword stores: for fixed m, lanes write consecutive addresses.
#pragma unroll
    for (int m = 0; m < 16; ++m) yr[base2 | (m << 6)] = w[m];
}

extern "C" void kernel_launch(void* const* d_in, const int* in_sizes, int n_in,
                              void* d_out, int out_size, void* d_ws, size_t ws_size,
                              hipStream_t stream) {
    (void)n_in; (void)d_ws; (void)ws_size; (void)out_size;
    const float* x = (const float*)d_in[0];  // [8192, 4096] fp32
    float* out = (float*)d_out;              // [8192, 4096] fp32
    const int rows = in_sizes[0] / N;        // 8192
    fwht4096_kernel<<<rows, 256, 0, stream>>>(x, out);
}

// Round 2
// 252.563 us; speedup vs baseline: 1.0109x; 1.0109x over previous
//
#include <hip/hip_runtime.h>

// out = x @ H, H = 4096x4096 Sylvester Hadamard (+/-1). H[i][j] =
// (-1)^popcount(i&j) is symmetric -> each output row is the Walsh-Hadamard
// transform of the input row: O(N log N) butterflies instead of a 275-GFLOP
// fp32 matmul. Memory-bound: 256 MiB total traffic, roofline ~43 us at
// 6.3 TB/s. H (d_in[1]) is never read.
//
// R2 change vs R1: epilogue was 16 scalar global_store_dword/thread
// (256 B/wave-inst). Now phase 2 writes back in-place to LDS (disjoint
// per-thread address sets -> no extra hazard barrier), one barrier, then
// 4x float4 nontemporal stores (1 KiB/wave-inst, output never re-read).

constexpr int N = 4096;

typedef float f32x4 __attribute__((ext_vector_type(4)));

// LDS bank-conflict swizzle: XOR bits 6-8 of the element index into bits 2-4.
// Preserves bits 0-1 -> float4 (16 B) alignment survives. All scalar phases
// land at worst 2 lanes/bank per wave (2-way aliasing is free on gfx950).
__device__ __forceinline__ int swz(int i) {
    return i ^ (((i >> 6) & 7) << 2);
}

__global__ __launch_bounds__(256) void fwht4096_kernel(const float* __restrict__ x,
                                                       float* __restrict__ out) {
    __shared__ __align__(16) float lds[N];
    const int t = threadIdx.x;
    const size_t rowoff = (size_t)blockIdx.x * N;
    const float* __restrict__ xr = x + rowoff;
    float* __restrict__ yr = out + rowoff;

    // ---- Phase 0: load i = 1024k + 4t + j (coalesced float4), stages on
    // bits 0,1 (j) and 10,11 (k): h = 1, 2, 1024, 2048.
    float r[4][4];
#pragma unroll
    for (int k = 0; k < 4; ++k) {
        const float4 v = *reinterpret_cast<const float4*>(xr + 1024 * k + 4 * t);
        r[k][0] = v.x; r[k][1] = v.y; r[k][2] = v.z; r[k][3] = v.w;
    }
#pragma unroll
    for (int k = 0; k < 4; ++k) {  // h=1 then h=2 (bits 0-1)
        float a0 = r[k][0] + r[k][1];
        float a1 = r[k][0] - r[k][1];
        float a2 = r[k][2] + r[k][3];
        float a3 = r[k][2] - r[k][3];
        r[k][0] = a0 + a2;
        r[k][1] = a1 + a3;
        r[k][2] = a0 - a2;
        r[k][3] = a1 - a3;
    }
#pragma unroll
    for (int j = 0; j < 4; ++j) {  // h=1024 then h=2048 (bits 10-11)
        float a0 = r[0][j] + r[1][j];
        float a1 = r[0][j] - r[1][j];
        float a2 = r[2][j] + r[3][j];
        float a3 = r[2][j] - r[3][j];
        r[0][j] = a0 + a2;
        r[1][j] = a1 + a3;
        r[2][j] = a0 - a2;
        r[3][j] = a1 - a3;
    }
#pragma unroll
    for (int k = 0; k < 4; ++k) {
        const int i0 = 1024 * k + 4 * t;
        *reinterpret_cast<float4*>(&lds[swz(i0)]) =
            make_float4(r[k][0], r[k][1], r[k][2], r[k][3]);
    }
    __syncthreads();

    // ---- Phase 1: own bits 2-5 (m), stages h = 4, 8, 16, 32.
    {
        float v[16];
        const int base1 = (t & 3) | (((t >> 2) & 15) << 6) | ((t >> 6) << 10);
#pragma unroll
        for (int m = 0; m < 16; ++m) v[m] = lds[swz(base1 | (m << 2))];
#pragma unroll
        for (int b = 1; b < 16; b <<= 1) {
#pragma unroll
            for (int m = 0; m < 16; ++m) {
                if ((m & b) == 0) {
                    const float a = v[m], c = v[m | b];
                    v[m]     = a + c;
                    v[m | b] = a - c;
                }
            }
        }
#pragma unroll
        for (int m = 0; m < 16; ++m) lds[swz(base1 | (m << 2))] = v[m];
    }
    __syncthreads();

    // ---- Phase 2: own bits 6-9 (m), stages h = 64, 128, 256, 512.
    // Write-back is IN-PLACE (thread writes exactly the slots it read; the
    // per-thread address sets partition the 4096 slots) -> no hazard barrier
    // between read and write.
    {
        float w[16];
        const int base2 = (t & 63) | ((t >> 6) << 10);
#pragma unroll
        for (int m = 0; m < 16; ++m) w[m] = lds[swz(base2 | (m << 6))];
#pragma unroll
        for (int b = 1; b < 16; b <<= 1) {
#pragma unroll
            for (int m = 0; m < 16; ++m) {
                if ((m & b) == 0) {
                    const float a = w[m], c = w[m | b];
                    w[m]     = a + c;
                    w[m | b] = a - c;
                }
            }
        }
#pragma unroll
        for (int m = 0; m < 16; ++m) lds[swz(base2 | (m << 6))] = w[m];
    }
    __syncthreads();

    // ---- Phase 3: vectorized epilogue. Re-read in the load layout (16B-
    // aligned b128, 2-way bank aliasing = free) and store 4x float4 per
    // thread: each wave store instruction covers a contiguous 1 KiB.
    // Nontemporal: out is never re-read by this kernel.
#pragma unroll
    for (int k = 0; k < 4; ++k) {
        const int i0 = 1024 * k + 4 * t;
        const f32x4 v = *reinterpret_cast<const f32x4*>(&lds[swz(i0)]);
        __builtin_nontemporal_store(v, reinterpret_cast<f32x4*>(yr + i0));
    }
}

extern "C" void kernel_launch(void* const* d_in, const int* in_sizes, int n_in,
                              void* d_out, int out_size, void* d_ws, size_t ws_size,
                              hipStream_t stream) {
    (void)n_in; (void)d_ws; (void)ws_size; (void)out_size;
    const float* x = (const float*)d_in[0];  // [8192, 4096] fp32
    float* out = (float*)d_out;              // [8192, 4096] fp32
    const int rows = in_sizes[0] / N;        // 8192
    fwht4096_kernel<<<rows, 256, 0, stream>>>(x, out);
}